// Round 1
// baseline (151.309 us; speedup 1.0000x reference)
//
#include <hip/hip_runtime.h>
#include <math.h>

#define NL   24
#define KEEP 12
#define DM   1024
#define BLK  256   // DM/4 threads, each owns 4 contiguous d-columns

__global__ __launch_bounds__(BLK) void lmask_kernel(const float* __restrict__ x,
                                                    const float* __restrict__ wg,
                                                    float* __restrict__ out) {
    const int token = blockIdx.x;
    const int tid   = threadIdx.x;
    const int lane  = tid & 63;
    const int wave  = tid >> 6;
    const int d0    = tid * 4;

    const float* xt = x + (size_t)token * (NL * DM);

    __shared__ float swave[4][NL];  // per-wave score partials
    __shared__ float s_w[NL];       // final softmax weights

    const float4 wv = *reinterpret_cast<const float4*>(wg + d0);

    // ---- load x once into registers; per-thread score partials ----
    float4 xr[NL];
    float  part[NL];
#pragma unroll
    for (int n = 0; n < NL; ++n) {
        xr[n] = *reinterpret_cast<const float4*>(xt + n * DM + d0);
        part[n] = xr[n].x * wv.x + xr[n].y * wv.y + xr[n].z * wv.z + xr[n].w * wv.w;
    }

    // ---- wave-level butterfly reduce each of the 24 partials ----
#pragma unroll
    for (int n = 0; n < NL; ++n) {
        float v = part[n];
        v += __shfl_xor(v, 1);
        v += __shfl_xor(v, 2);
        v += __shfl_xor(v, 4);
        v += __shfl_xor(v, 8);
        v += __shfl_xor(v, 16);
        v += __shfl_xor(v, 32);
        part[n] = v;
    }
    if (lane == 0) {
#pragma unroll
        for (int n = 0; n < NL; ++n) swave[wave][n] = part[n];
    }
    __syncthreads();

    // ---- wave 0: final scores, top-KEEP mask, softmax weights ----
    if (tid < 64) {
        float sc_own = -INFINITY;
        if (lane < NL)
            sc_own = swave[0][lane] + swave[1][lane] + swave[2][lane] + swave[3][lane];

        // rank = #(strictly greater) + #(equal with lower index)  -> stable top_k
        int rank = 0;
#pragma unroll
        for (int m = 0; m < NL; ++m) {
            float scm = swave[0][m] + swave[1][m] + swave[2][m] + swave[3][m]; // broadcast reads
            rank += ((scm > sc_own) || (scm == sc_own && m < lane)) ? 1 : 0;
        }
        const bool keep = (lane < NL) && (rank < KEEP);

        float val = keep ? sc_own : -INFINITY;
        float mx = val;
        mx = fmaxf(mx, __shfl_xor(mx, 1));
        mx = fmaxf(mx, __shfl_xor(mx, 2));
        mx = fmaxf(mx, __shfl_xor(mx, 4));
        mx = fmaxf(mx, __shfl_xor(mx, 8));
        mx = fmaxf(mx, __shfl_xor(mx, 16));
        mx = fmaxf(mx, __shfl_xor(mx, 32));

        float e = keep ? __expf(sc_own - mx) : 0.0f;
        float s = e;
        s += __shfl_xor(s, 1);
        s += __shfl_xor(s, 2);
        s += __shfl_xor(s, 4);
        s += __shfl_xor(s, 8);
        s += __shfl_xor(s, 16);
        s += __shfl_xor(s, 32);

        if (lane < NL) s_w[lane] = e / s;
    }
    __syncthreads();

    // ---- weighted layer sum from registers ----
    float4 acc = make_float4(0.f, 0.f, 0.f, 0.f);
#pragma unroll
    for (int n = 0; n < NL; ++n) {
        const float w = s_w[n];  // LDS broadcast
        acc.x = fmaf(w, xr[n].x, acc.x);
        acc.y = fmaf(w, xr[n].y, acc.y);
        acc.z = fmaf(w, xr[n].z, acc.z);
        acc.w = fmaf(w, xr[n].w, acc.w);
    }
    reinterpret_cast<float4*>(out + (size_t)token * DM)[tid] = acc;
}

extern "C" void kernel_launch(void* const* d_in, const int* in_sizes, int n_in,
                              void* d_out, int out_size, void* d_ws, size_t ws_size,
                              hipStream_t stream) {
    const float* x  = (const float*)d_in[0];
    const float* wg = (const float*)d_in[1];
    float* out      = (float*)d_out;
    const int tokens = in_sizes[0] / (NL * DM);  // B*T = 8000
    lmask_kernel<<<tokens, BLK, 0, stream>>>(x, wg, out);
}

// Round 2
// 147.031 us; speedup vs baseline: 1.0291x; 1.0291x over previous
//
#include <hip/hip_runtime.h>
#include <math.h>

#define NL    24
#define KEEP  12
#define DM    1024
#define BLK   1024
#define LPT   6          // layers per thread = NL/4 quarters

__global__ __launch_bounds__(BLK, 8) void lmask_kernel(const float* __restrict__ x,
                                                       const float* __restrict__ wg,
                                                       float* __restrict__ out) {
    const int token = blockIdx.x;
    const int tid   = threadIdx.x;
    const int lane  = tid & 63;
    const int wave  = tid >> 6;        // 0..15
    const int q     = tid >> 8;        // layer-quarter 0..3
    const int colg  = tid & 255;       // column group (4 cols each)
    const int d0    = colg * 4;
    const int nbase = q * LPT;

    const float* xt = x + (size_t)token * (NL * DM);

    __shared__ float  swave[16][LPT];  // per-wave score partials
    __shared__ float4 pacc[3][256];    // quarter partial outputs

    const float4 wv = *reinterpret_cast<const float4*>(wg + d0);

    // ---- load this quarter's 6 layers once; per-thread score partials ----
    float4 xr[LPT];
    float  part[LPT];
#pragma unroll
    for (int j = 0; j < LPT; ++j) {
        xr[j]   = *reinterpret_cast<const float4*>(xt + (nbase + j) * DM + d0);
        part[j] = xr[j].x * wv.x + xr[j].y * wv.y + xr[j].z * wv.z + xr[j].w * wv.w;
    }

    // ---- wave butterfly reduce (6 values x 6 stages) ----
#pragma unroll
    for (int j = 0; j < LPT; ++j) {
        float v = part[j];
        v += __shfl_xor(v, 1);
        v += __shfl_xor(v, 2);
        v += __shfl_xor(v, 4);
        v += __shfl_xor(v, 8);
        v += __shfl_xor(v, 16);
        v += __shfl_xor(v, 32);
        part[j] = v;
    }
    if (lane == 0) {
#pragma unroll
        for (int j = 0; j < LPT; ++j) swave[wave][j] = part[j];
    }
    __syncthreads();

    // ---- redundant per-wave softmax (keeps every wave busy, no 2nd barrier) ----
    float sc = -INFINITY;
    if (lane < NL) {
        const int qn = lane / LPT, jn = lane % LPT;
        sc = swave[4*qn + 0][jn] + swave[4*qn + 1][jn]
           + swave[4*qn + 2][jn] + swave[4*qn + 3][jn];
    }
    // stable top-k rank: #(strictly greater) + #(equal with lower index)
    int rank = 0;
#pragma unroll
    for (int m = 0; m < NL; ++m) {
        const float sm = __shfl(sc, m);
        rank += ((sm > sc) || (sm == sc && m < lane)) ? 1 : 0;
    }
    const bool keep = (lane < NL) && (rank < KEEP);

    float val = keep ? sc : -INFINITY;   // lanes >= NL contribute -inf
    float mx = val;
    mx = fmaxf(mx, __shfl_xor(mx, 1));
    mx = fmaxf(mx, __shfl_xor(mx, 2));
    mx = fmaxf(mx, __shfl_xor(mx, 4));
    mx = fmaxf(mx, __shfl_xor(mx, 8));
    mx = fmaxf(mx, __shfl_xor(mx, 16));  // reduce within 32-lane half (lanes 0..23 together)

    float e = keep ? __expf(sc - mx) : 0.0f;
    float s = e;
    s += __shfl_xor(s, 1);
    s += __shfl_xor(s, 2);
    s += __shfl_xor(s, 4);
    s += __shfl_xor(s, 8);
    s += __shfl_xor(s, 16);
    const float wfin = e / s;            // valid on lanes 0..23 of every wave

    // ---- weighted partial sum over this quarter's layers ----
    float4 acc = make_float4(0.f, 0.f, 0.f, 0.f);
#pragma unroll
    for (int j = 0; j < LPT; ++j) {
        const float w = __shfl(wfin, nbase + j);   // uniform index per wave
        acc.x = fmaf(w, xr[j].x, acc.x);
        acc.y = fmaf(w, xr[j].y, acc.y);
        acc.z = fmaf(w, xr[j].z, acc.z);
        acc.w = fmaf(w, xr[j].w, acc.w);
    }

    if (q > 0) pacc[q - 1][colg] = acc;
    __syncthreads();

    if (q == 0) {
        const float4 a = pacc[0][colg];
        const float4 b = pacc[1][colg];
        const float4 c = pacc[2][colg];
        acc.x += a.x + b.x + c.x;
        acc.y += a.y + b.y + c.y;
        acc.z += a.z + b.z + c.z;
        acc.w += a.w + b.w + c.w;
        reinterpret_cast<float4*>(out + (size_t)token * DM)[colg] = acc;
    }
}

extern "C" void kernel_launch(void* const* d_in, const int* in_sizes, int n_in,
                              void* d_out, int out_size, void* d_ws, size_t ws_size,
                              hipStream_t stream) {
    const float* x  = (const float*)d_in[0];
    const float* wg = (const float*)d_in[1];
    float* out      = (float*)d_out;
    const int tokens = in_sizes[0] / (NL * DM);  // B*T = 8000
    lmask_kernel<<<tokens, BLK, 0, stream>>>(x, wg, out);
}

// Round 4
// 133.001 us; speedup vs baseline: 1.1377x; 1.1055x over previous
//
#include <hip/hip_runtime.h>
#include <math.h>

#define NL    24
#define KEEP  12
#define DM    1024
#define BLK   1024
#define LPT   6          // layers per thread = NL/4 quarters

typedef float f4 __attribute__((ext_vector_type(4)));  // native vector for nontemporal builtins

__global__ __launch_bounds__(BLK, 8) void lmask_kernel(const float* __restrict__ x,
                                                       const float* __restrict__ wg,
                                                       float* __restrict__ out) {
    const int token = blockIdx.x;
    const int tid   = threadIdx.x;
    const int lane  = tid & 63;
    const int wave  = tid >> 6;        // 0..15
    const int q     = tid >> 8;        // layer-quarter 0..3
    const int colg  = tid & 255;       // column group (4 cols each)
    const int d0    = colg * 4;
    const int nbase = q * LPT;

    const float* xt = x + (size_t)token * (NL * DM);

    __shared__ float swave[16][LPT];   // per-wave score partials
    __shared__ f4    pacc[3][256];     // quarter partial outputs

    const f4 wv = *reinterpret_cast<const f4*>(wg + d0);  // reused -> cached load

    // ---- load this quarter's 6 layers once (streaming, no reuse -> nt) ----
    f4    xr[LPT];
    float part[LPT];
#pragma unroll
    for (int j = 0; j < LPT; ++j) {
        xr[j]   = __builtin_nontemporal_load(
                      reinterpret_cast<const f4*>(xt + (nbase + j) * DM + d0));
        part[j] = xr[j].x * wv.x + xr[j].y * wv.y + xr[j].z * wv.z + xr[j].w * wv.w;
    }

    // ---- wave butterfly reduce (6 values x 6 stages) ----
#pragma unroll
    for (int j = 0; j < LPT; ++j) {
        float v = part[j];
        v += __shfl_xor(v, 1);
        v += __shfl_xor(v, 2);
        v += __shfl_xor(v, 4);
        v += __shfl_xor(v, 8);
        v += __shfl_xor(v, 16);
        v += __shfl_xor(v, 32);
        part[j] = v;
    }
    if (lane == 0) {
#pragma unroll
        for (int j = 0; j < LPT; ++j) swave[wave][j] = part[j];
    }
    __syncthreads();

    // ---- redundant per-wave softmax (keeps every wave busy) ----
    float sc = -INFINITY;
    if (lane < NL) {
        const int qn = lane / LPT, jn = lane % LPT;
        sc = swave[4*qn + 0][jn] + swave[4*qn + 1][jn]
           + swave[4*qn + 2][jn] + swave[4*qn + 3][jn];
    }
    // stable top-k rank: #(strictly greater) + #(equal with lower index)
    int rank = 0;
#pragma unroll
    for (int m = 0; m < NL; ++m) {
        const float sm = __shfl(sc, m);
        rank += ((sm > sc) || (sm == sc && m < lane)) ? 1 : 0;
    }
    const bool keep = (lane < NL) && (rank < KEEP);

    float val = keep ? sc : -INFINITY;
    float mx = val;
    mx = fmaxf(mx, __shfl_xor(mx, 1));
    mx = fmaxf(mx, __shfl_xor(mx, 2));
    mx = fmaxf(mx, __shfl_xor(mx, 4));
    mx = fmaxf(mx, __shfl_xor(mx, 8));
    mx = fmaxf(mx, __shfl_xor(mx, 16));

    float e = keep ? __expf(sc - mx) : 0.0f;
    float s = e;
    s += __shfl_xor(s, 1);
    s += __shfl_xor(s, 2);
    s += __shfl_xor(s, 4);
    s += __shfl_xor(s, 8);
    s += __shfl_xor(s, 16);
    const float wfin = e / s;            // valid on lanes 0..23 of every wave

    // ---- weighted partial sum over this quarter's layers ----
    f4 acc = (f4)(0.0f);
#pragma unroll
    for (int j = 0; j < LPT; ++j) {
        const float w = __shfl(wfin, nbase + j);   // uniform index per wave
        acc.x = fmaf(w, xr[j].x, acc.x);
        acc.y = fmaf(w, xr[j].y, acc.y);
        acc.z = fmaf(w, xr[j].z, acc.z);
        acc.w = fmaf(w, xr[j].w, acc.w);
    }

    if (q > 0) pacc[q - 1][colg] = acc;
    __syncthreads();

    if (q == 0) {
        const f4 a = pacc[0][colg];
        const f4 b = pacc[1][colg];
        const f4 c = pacc[2][colg];
        acc += a + b + c;
        __builtin_nontemporal_store(acc,
            reinterpret_cast<f4*>(out + (size_t)token * DM) + colg);
    }
}

extern "C" void kernel_launch(void* const* d_in, const int* in_sizes, int n_in,
                              void* d_out, int out_size, void* d_ws, size_t ws_size,
                              hipStream_t stream) {
    const float* x  = (const float*)d_in[0];
    const float* wg = (const float*)d_in[1];
    float* out      = (float*)d_out;
    const int tokens = in_sizes[0] / (NL * DM);  // B*T = 8000
    lmask_kernel<<<tokens, BLK, 0, stream>>>(x, wg, out);
}